// Round 1
// baseline (764.574 us; speedup 1.0000x reference)
//
#include <hip/hip_runtime.h>

// BetaBernoulliMixture: per row r, per time t:
//   s_prev = #ones in obs[r, 0..t-1];  f_prev = t - s_prev
//   a1 = alpha1+s_prev, b1 = beta1+f_prev, a2 = alpha2+s_prev, b2 = beta2+f_prev
//   d(t) = clog2 - clog1 = sum_{u<t} [ log(sel2_u*(A1+u)) - log(sel1_u*(A2+u)) ]
//     where sel_k = obs_u ? (alpha_k+s_prev(u)) : (beta_k+u-s_prev(u)),
//           A_k = alpha_k + beta_k
//   post_mixweight = w / (w + (1-w)*exp(d))
// Output layout: [5, B, T] = {a1, b1, a2, b2, post_mixweight}

#define BLOCK 256

__global__ __launch_bounds__(BLOCK) void bbm_kernel(
    const float* __restrict__ obs,
    const float* __restrict__ alpha1, const float* __restrict__ beta1,
    const float* __restrict__ alpha2, const float* __restrict__ beta2,
    const float* __restrict__ mixw,
    float* __restrict__ out,
    int T, size_t bt_stride)
{
    const int row  = blockIdx.x;
    const int tid  = threadIdx.x;
    const int lane = tid & 63;
    const int wid  = tid >> 6;

    __shared__ int   sPart[4];
    __shared__ float dPart[4];

    const float A1 = alpha1[row], B1 = beta1[row];
    const float A2 = alpha2[row], B2 = beta2[row];
    const float w  = mixw[0];
    const float AB1 = A1 + B1, AB2 = A2 + B2;
    const float w2 = 1.0f - w;

    const float* __restrict__ orow = obs + (size_t)row * T;
    float* __restrict__ obase = out + (size_t)row * T;

    int   carry_s = 0;
    float carry_d = 0.0f;

    const int segs = T / BLOCK;
    for (int seg = 0; seg < segs; ++seg) {
        const int t = seg * BLOCK + tid;
        const float ov = orow[t];
        const int bit = (ov > 0.5f) ? 1 : 0;

        // ---- block exclusive scan of bit (wave shuffle scan + LDS combine) ----
        int incl_s = bit;
        #pragma unroll
        for (int off = 1; off < 64; off <<= 1) {
            int n = __shfl_up(incl_s, off, 64);
            if (lane >= off) incl_s += n;
        }
        if (lane == 63) sPart[wid] = incl_s;
        __syncthreads();
        int prior_s = 0, total_s = 0;
        #pragma unroll
        for (int wI = 0; wI < 4; ++wI) {
            int p = sPart[wI];
            total_s += p;
            if (wI < wid) prior_s += p;
        }
        const int s_prev = carry_s + prior_s + (incl_s - bit);

        // ---- pointwise posterior params + per-step delta ----
        const float ft     = (float)t;
        const float fs     = (float)s_prev;
        const float f_prev = ft - fs;
        const float a1v = A1 + fs,     b1v = B1 + f_prev;
        const float a2v = A2 + fs,     b2v = B2 + f_prev;
        const float sel1 = bit ? a1v : b1v;
        const float sel2 = bit ? a2v : b2v;
        // delta = log(sel2) + log(AB1+t) - log(sel1) - log(AB2+t)
        const float delta = __logf(sel2 * (AB1 + ft)) - __logf(sel1 * (AB2 + ft));

        // ---- block exclusive scan of delta ----
        float incl_d = delta;
        #pragma unroll
        for (int off = 1; off < 64; off <<= 1) {
            float n = __shfl_up(incl_d, off, 64);
            if (lane >= off) incl_d += n;
        }
        if (lane == 63) dPart[wid] = incl_d;
        __syncthreads();
        float prior_d = 0.0f, total_d = 0.0f;
        #pragma unroll
        for (int wI = 0; wI < 4; ++wI) {
            float p = dPart[wI];
            total_d += p;
            if (wI < wid) prior_d += p;
        }
        const float d = carry_d + prior_d + (incl_d - delta);

        // ---- outputs ----
        const float e  = __expf(d);
        const float pm = w / (w + w2 * e);

        obase[t]                 = a1v;
        obase[t +     bt_stride] = b1v;
        obase[t + 2 * bt_stride] = a2v;
        obase[t + 3 * bt_stride] = b2v;
        obase[t + 4 * bt_stride] = pm;

        carry_s += total_s;
        carry_d += total_d;
    }
}

extern "C" void kernel_launch(void* const* d_in, const int* in_sizes, int n_in,
                              void* d_out, int out_size, void* d_ws, size_t ws_size,
                              hipStream_t stream) {
    const float* obs    = (const float*)d_in[0];
    const float* alpha1 = (const float*)d_in[1];
    const float* beta1  = (const float*)d_in[2];
    const float* alpha2 = (const float*)d_in[3];
    const float* beta2  = (const float*)d_in[4];
    const float* mixw   = (const float*)d_in[5];

    const int Bn = in_sizes[1];
    const int Tn = in_sizes[0] / Bn;
    const size_t bt = (size_t)Bn * (size_t)Tn;

    bbm_kernel<<<Bn, BLOCK, 0, stream>>>(obs, alpha1, beta1, alpha2, beta2,
                                         mixw, (float*)d_out, Tn, bt);
}